// Round 6
// baseline (302.218 us; speedup 1.0000x reference)
//
#include <hip/hip_runtime.h>

typedef unsigned short u16;
typedef unsigned int   u32;
typedef unsigned long long u64;
typedef __attribute__((ext_vector_type(8))) short short8;
typedef __attribute__((ext_vector_type(4))) float f32x4;

#define T_TOK 8192
#define DIM   1024
#define NEXP  8
#define NPAIR (T_TOK * 2)   // 16384 token-expert pairs
#define MAXTILES 72         // sum ceil(cnt_e/256) <= 64 + 7; 72 % 8 == 0
#define NCASTBLK 12288      // 3*8388608/2048

__device__ __forceinline__ u16 f2bf(float f) {
  u32 u = __builtin_bit_cast(u32, f);
  u32 r = (u + 0x7fffu + ((u >> 16) & 1u)) >> 16;  // RNE
  return (u16)r;
}
__device__ __forceinline__ float bf2f(u16 b) {
  return __builtin_bit_cast(float, ((u32)b) << 16);
}

__device__ __forceinline__ void gl_lds16(const u16* g, u16* l) {
  __builtin_amdgcn_global_load_lds(
      (const __attribute__((address_space(1))) u32*)g,
      (__attribute__((address_space(3))) u32*)l,
      16, 0, 0);
}

// ------- fused: fp32->bf16 cast of x,W1,W2 (blocks 0..12287) + expert
// ------- bucket sort (block 12288, ballot-based, no atomics) -----------------
__global__ void cast_sort_k(const float* __restrict__ x, const float* __restrict__ W1,
                            const float* __restrict__ W2,
                            u16* __restrict__ xb, u16* __restrict__ w1b, u16* __restrict__ w2b,
                            const int* __restrict__ idx,
                            int* __restrict__ counts, int* __restrict__ offsets,
                            int* __restrict__ bucket, int* __restrict__ pos,
                            int* __restrict__ tlist, int* __restrict__ ntiles) {
  if (blockIdx.x < NCASTBLK) {
    const int g = (blockIdx.x * 256 + threadIdx.x) * 8;
    const int region = g >> 23;
    const int i = g & 0x7fffff;
    const float* s = (region == 0) ? x : (region == 1) ? W1 : W2;
    u16* d = (region == 0) ? xb : (region == 1) ? w1b : w2b;
    f32x4 a = *(const f32x4*)(s + i);
    f32x4 b = *(const f32x4*)(s + i + 4);
    short8 o;
    o[0] = (short)f2bf(a[0]); o[1] = (short)f2bf(a[1]);
    o[2] = (short)f2bf(a[2]); o[3] = (short)f2bf(a[3]);
    o[4] = (short)f2bf(b[0]); o[5] = (short)f2bf(b[1]);
    o[6] = (short)f2bf(b[2]); o[7] = (short)f2bf(b[3]);
    *(short8*)(d + i) = o;
    return;
  }

  // ---- sort block: 256 threads = 4 waves, each owns 4096 contiguous items.
  __shared__ int lc[4][NEXP];
  __shared__ int lo[4][NEXP];
  const int tid  = threadIdx.x;
  const int w    = tid >> 6;
  const int lane = tid & 63;
  const u64 ltmask = (lane == 63) ? 0x7fffffffffffffffull : ((1ull << lane) - 1);

  int cnt[NEXP] = {};
  for (int i = 0; i < 64; ++i) {
    const int e = idx[w * 4096 + i * 64 + lane];
#pragma unroll
    for (int ex = 0; ex < NEXP; ++ex) {
      u64 m = __ballot(e == ex);
      cnt[ex] += (int)__popcll(m);
    }
  }
  if (lane == 0) {
#pragma unroll
    for (int ex = 0; ex < NEXP; ++ex) lc[w][ex] = cnt[ex];
  }
  __syncthreads();

  if (tid == 0) {
    int s = 0;
    int c8[NEXP];
    for (int ex = 0; ex < NEXP; ++ex) {
      offsets[ex] = s;
      int c = 0;
      for (int ww = 0; ww < 4; ++ww) { lo[ww][ex] = s; s += lc[ww][ex]; c += lc[ww][ex]; }
      counts[ex] = c;
      c8[ex] = c;
    }
    int t = 0;  // round-robin: tile slot p -> expert p%8 while rounds full
    for (int r = 0; r < 64; ++r)
      for (int ex = 0; ex < NEXP; ++ex)
        if (r * 256 < c8[ex]) tlist[t++] = (r << 3) | ex;
    *ntiles = t;
  }
  __syncthreads();

  int cur[NEXP];
#pragma unroll
  for (int ex = 0; ex < NEXP; ++ex) cur[ex] = lo[w][ex];
  for (int i = 0; i < 64; ++i) {
    const int item = w * 4096 + i * 64 + lane;
    const int e = idx[item];
    int p = 0;
#pragma unroll
    for (int ex = 0; ex < NEXP; ++ex) {
      u64 m = __ballot(e == ex);
      int rank = (int)__popcll(m & ltmask);
      if (e == ex) p = cur[ex] + rank;
      cur[ex] += (int)__popcll(m);
    }
    bucket[p] = item;
    pos[item] = p;
  }
}

// ---------------- grouped GEMM: O[p] = relu(Arow[p] @ W[e]^T), bf16 ----------
// 256x128x64 tiles (85 FLOP/B of LDS staging vs 64 for 128^2), 512 threads =
// 8 waves (4m x 2n of 64x64, 4x4 frags each), single-buffered 48KB LDS,
// XOR-swizzled (bank-conflict-free), global_load_lds width-16 staging,
// 16x16x32 bf16 MFMA. Grid (MAXTILES, 8): x = tile slot, expert = slot%8
// (round-robin tlist) -> XCD pinning since gridDim.x % 8 == 0.
template <int GATHER>
__global__ __launch_bounds__(512, 4)
void moe_gemm_k(const u16* __restrict__ A,
                const u16* __restrict__ W,
                u16* __restrict__ O,
                const int* __restrict__ counts,
                const int* __restrict__ offsets,
                const int* __restrict__ bucket,
                const int* __restrict__ tlist,
                const int* __restrict__ ntiles) {
  if ((int)blockIdx.x >= *ntiles) return;
  const int info = tlist[blockIdx.x];
  const int e    = info & 7;
  const int m0   = (info >> 3) << 8;   // x256 rows
  const int cnt  = counts[e];
  const int seg  = offsets[e];
  const int n0   = blockIdx.y << 7;

  __shared__ u16 As[256 * 64];  // 32 KB, [r][64] with chunk swizzle
  __shared__ u16 Bs[128 * 64];  // 16 KB

  const int tid  = threadIdx.x;
  const int lane = tid & 63;
  const int wave = tid >> 6;

  // A: 2048 16B-chunks, 4 per wave-lane; B: 1024 chunks, 2 per wave-lane.
  int aoff[4], boff[2];
#pragma unroll
  for (int j = 0; j < 4; ++j) {
    const int c   = ((wave << 2) + j) * 64 + lane;  // 0..2047
    const int r   = c >> 3;                         // 0..255
    const int c16 = (c & 7) ^ (r & 7);
    int p = seg + m0 + r;
    p = (p < seg + cnt) ? p : (seg + cnt - 1);      // clamp tail rows
    int rowbase;
    if (GATHER) { const int pair = bucket[p]; rowbase = (pair >> 1) * DIM; }
    else        { rowbase = p * DIM; }
    aoff[j] = rowbase + (c16 << 3);
  }
#pragma unroll
  for (int j = 0; j < 2; ++j) {
    const int c   = ((wave << 1) + j) * 64 + lane;  // 0..1023
    const int r   = c >> 3;                         // 0..127
    const int c16 = (c & 7) ^ (r & 7);
    boff[j] = e * DIM * DIM + (n0 + r) * DIM + (c16 << 3);
  }

  f32x4 acc[4][4] = {};

  const int wm   = (wave >> 1) << 6;   // 0,64,128,192
  const int wn   = (wave & 1) << 6;    // 0,64
  const int lr   = lane & 15;
  const int quad = lane >> 4;

  for (int k0 = 0; k0 < DIM; k0 += 64) {
    __syncthreads();  // protect LDS reuse
#pragma unroll
    for (int j = 0; j < 4; ++j)
      gl_lds16(A + aoff[j] + k0, &As[((wave << 2) + j) << 9]);
#pragma unroll
    for (int j = 0; j < 2; ++j)
      gl_lds16(W + boff[j] + k0, &Bs[((wave << 1) + j) << 9]);
    __syncthreads();  // drains vmcnt for global_load_lds

#pragma unroll
    for (int kk = 0; kk < 64; kk += 32) {
      const int qb = (kk >> 3) + quad;  // wanted global chunk
      short8 af[4], bf[4];
#pragma unroll
      for (int mi = 0; mi < 4; ++mi) {
        const int r = wm + (mi << 4) + lr;
        af[mi] = *(const short8*)&As[r * 64 + ((qb ^ (r & 7)) << 3)];
      }
#pragma unroll
      for (int ni = 0; ni < 4; ++ni) {
        const int r = wn + (ni << 4) + lr;
        bf[ni] = *(const short8*)&Bs[r * 64 + ((qb ^ (r & 7)) << 3)];
      }
#pragma unroll
      for (int mi = 0; mi < 4; ++mi)
#pragma unroll
        for (int ni = 0; ni < 4; ++ni)
          acc[mi][ni] = __builtin_amdgcn_mfma_f32_16x16x32_bf16(af[mi], bf[ni], acc[mi][ni], 0, 0, 0);
    }
  }

  // Epilogue: relu -> bf16. C/D layout: col = lane&15, row = quad*4 + reg.
  const int pend = seg + cnt;
#pragma unroll
  for (int mi = 0; mi < 4; ++mi) {
#pragma unroll
    for (int ni = 0; ni < 4; ++ni) {
      const int col = n0 + wn + (ni << 4) + lr;
#pragma unroll
      for (int r4 = 0; r4 < 4; ++r4) {
        const int p = seg + m0 + wm + (mi << 4) + (quad << 2) + r4;
        if (p < pend) {
          float v = acc[mi][ni][r4];
          v = v > 0.f ? v : 0.f;
          O[(size_t)p * DIM + col] = f2bf(v);
        }
      }
    }
  }
}

// ---------------- combine: out[t] = w0*y[pos[2t]] + w1*y[pos[2t+1]] ----------
__global__ void combine_k(const u16* __restrict__ y, const int* __restrict__ pos,
                          const float* __restrict__ wts, float* __restrict__ out) {
  const int t    = blockIdx.x * 2 + (threadIdx.x >> 7);
  const int lane = threadIdx.x & 127;
  const int col  = lane * 8;
  const int p0 = pos[2 * t], p1 = pos[2 * t + 1];
  const float w0 = wts[2 * t], w1 = wts[2 * t + 1];
  const short8 a = *(const short8*)(y + (size_t)p0 * DIM + col);
  const short8 b = *(const short8*)(y + (size_t)p1 * DIM + col);
  f32x4 o0, o1;
#pragma unroll
  for (int j = 0; j < 8; ++j) {
    float v = w0 * bf2f((u16)a[j]) + w1 * bf2f((u16)b[j]);
    if (j < 4) o0[j] = v; else o1[j - 4] = v;
  }
  float* op = out + (size_t)t * DIM + col;
  *(f32x4*)op = o0;
  *(f32x4*)(op + 4) = o1;
}

extern "C" void kernel_launch(void* const* d_in, const int* in_sizes, int n_in,
                              void* d_out, int out_size, void* d_ws, size_t ws_size,
                              hipStream_t stream) {
  const float* x   = (const float*)d_in[0];
  const int*   idx = (const int*)d_in[1];
  const float* wts = (const float*)d_in[2];
  const float* W1  = (const float*)d_in[3];
  const float* W2  = (const float*)d_in[4];
  float* out = (float*)d_out;

  char* ws = (char*)d_ws;
  int* counts  = (int*)ws;                       // 8
  int* offsets = (int*)(ws + 32);                // 8
  int* ntiles  = (int*)(ws + 64);                // 1
  int* tlist   = (int*)(ws + 128);               // <=72
  int* bucket  = (int*)(ws + 1024);              // 16384
  int* pos     = (int*)(ws + 1024 + 4 * NPAIR);  // 16384
  const size_t base = 132096;                    // 16B-aligned
  const size_t MB16 = 16ull * 1024 * 1024;
  u16* xb  = (u16*)(ws + base);                  // 16 MB
  u16* w1b = (u16*)(ws + base + MB16);           // 16 MB
  u16* w2b = (u16*)(ws + base + 2 * MB16);       // 16 MB
  u16* h   = (u16*)(ws + base + 3 * MB16);       // 32 MB
  u16* yb  = xb;                                 // 32 MB, aliases xb+w1b (dead)

  cast_sort_k<<<NCASTBLK + 1, 256, 0, stream>>>(x, W1, W2, xb, w1b, w2b,
                                                idx, counts, offsets, bucket, pos,
                                                tlist, ntiles);

  dim3 gg(MAXTILES, DIM / 128);  // (72, 8): x = tile slot -> XCD = expert
  moe_gemm_k<1><<<gg, 512, 0, stream>>>(xb, w1b, h, counts, offsets, bucket, tlist, ntiles);
  moe_gemm_k<0><<<gg, 512, 0, stream>>>(h, w2b, yb, counts, offsets, bucket, tlist, ntiles);

  combine_k<<<T_TOK / 2, 256, 0, stream>>>(yb, pos, wts, out);
}

// Round 7
// 295.091 us; speedup vs baseline: 1.0242x; 1.0242x over previous
//
#include <hip/hip_runtime.h>

typedef unsigned short u16;
typedef unsigned int   u32;
typedef unsigned long long u64;
typedef __attribute__((ext_vector_type(8))) short short8;
typedef __attribute__((ext_vector_type(4))) float f32x4;

#define T_TOK 8192
#define DIM   1024
#define NEXP  8
#define NPAIR (T_TOK * 2)   // 16384 token-expert pairs
#define MAXTILES 72         // sum ceil(cnt_e/256) <= 64 + 7; 72 % 8 == 0
#define CASTBLK 3072        // 3*8388608 / (1024*8)
#define ZEROBLK 1024        // 8388608 / (1024*8)

__device__ __forceinline__ u16 f2bf(float f) {
  u32 u = __builtin_bit_cast(u32, f);
  u32 r = (u + 0x7fffu + ((u >> 16) & 1u)) >> 16;  // RNE
  return (u16)r;
}

__device__ __forceinline__ void gl_lds16(const u16* g, u16* l) {
  __builtin_amdgcn_global_load_lds(
      (const __attribute__((address_space(1))) u32*)g,
      (__attribute__((address_space(3))) u32*)l,
      16, 0, 0);
}

// ---- K1: block 0 = 16-wave ballot sort (starts first); blocks 1..3072 =
// ---- fp32->bf16 cast of x,W1,W2; blocks 3073..4096 = zero d_out. ------------
__global__ __launch_bounds__(1024)
void prep_k(const float* __restrict__ x, const float* __restrict__ W1,
            const float* __restrict__ W2,
            u16* __restrict__ xb, u16* __restrict__ w1b, u16* __restrict__ w2b,
            const int* __restrict__ idx,
            int* __restrict__ counts, int* __restrict__ offsets,
            int* __restrict__ bucket,
            int* __restrict__ tlist, int* __restrict__ ntiles,
            float* __restrict__ out) {
  const int tid = threadIdx.x;
  if (blockIdx.x >= 1 && blockIdx.x <= CASTBLK) {
    const int g = ((int)blockIdx.x - 1) * 8192 + tid * 8;  // 0 .. 3*8388608
    const int region = g >> 23;
    const int i = g & 0x7fffff;
    const float* s = (region == 0) ? x : (region == 1) ? W1 : W2;
    u16* d = (region == 0) ? xb : (region == 1) ? w1b : w2b;
    f32x4 a = *(const f32x4*)(s + i);
    f32x4 b = *(const f32x4*)(s + i + 4);
    short8 o;
    o[0] = (short)f2bf(a[0]); o[1] = (short)f2bf(a[1]);
    o[2] = (short)f2bf(a[2]); o[3] = (short)f2bf(a[3]);
    o[4] = (short)f2bf(b[0]); o[5] = (short)f2bf(b[1]);
    o[6] = (short)f2bf(b[2]); o[7] = (short)f2bf(b[3]);
    *(short8*)(d + i) = o;
    return;
  }
  if (blockIdx.x > CASTBLK) {  // zero out (G2 accumulates into it atomically)
    const int i = ((int)blockIdx.x - CASTBLK - 1) * 8192 + tid * 8;
    f32x4 z = {0.f, 0.f, 0.f, 0.f};
    *(f32x4*)(out + i) = z;
    *(f32x4*)(out + i + 4) = z;
    return;
  }

  // ---- sort block (blockIdx 0): 16 waves, each owns 1024 contiguous items.
  __shared__ int lc[16][NEXP];
  __shared__ int lo[16][NEXP];
  const int w    = tid >> 6;
  const int lane = tid & 63;
  const u64 ltmask = (lane == 63) ? 0x7fffffffffffffffull : ((1ull << lane) - 1);

  int e_i[16];
#pragma unroll
  for (int i = 0; i < 16; ++i) e_i[i] = idx[(w * 16 + i) * 64 + lane];

  int cnt[NEXP] = {};
#pragma unroll
  for (int i = 0; i < 16; ++i) {
#pragma unroll
    for (int ex = 0; ex < NEXP; ++ex) {
      u64 m = __ballot(e_i[i] == ex);
      cnt[ex] += (int)__popcll(m);
    }
  }
  if (lane == 0) {
#pragma unroll
    for (int ex = 0; ex < NEXP; ++ex) lc[w][ex] = cnt[ex];
  }
  __syncthreads();

  if (tid == 0) {
    int s = 0;
    int c8[NEXP];
    for (int ex = 0; ex < NEXP; ++ex) {
      offsets[ex] = s;
      int c = 0;
      for (int ww = 0; ww < 16; ++ww) { lo[ww][ex] = s; s += lc[ww][ex]; c += lc[ww][ex]; }
      counts[ex] = c;
      c8[ex] = c;
    }
    int t = 0;  // round-robin: tile slot p -> expert p%8 while rounds full
    for (int r = 0; r < 64; ++r)
      for (int ex = 0; ex < NEXP; ++ex)
        if (r * 256 < c8[ex]) tlist[t++] = (r << 3) | ex;
    *ntiles = t;
  }
  __syncthreads();

  int cur[NEXP];
#pragma unroll
  for (int ex = 0; ex < NEXP; ++ex) cur[ex] = lo[w][ex];
#pragma unroll
  for (int i = 0; i < 16; ++i) {
    const int item = (w * 16 + i) * 64 + lane;
    const int e = e_i[i];
    int p = 0;
#pragma unroll
    for (int ex = 0; ex < NEXP; ++ex) {
      u64 m = __ballot(e == ex);
      int rank = (int)__popcll(m & ltmask);
      if (e == ex) p = cur[ex] + rank;
      cur[ex] += (int)__popcll(m);
    }
    bucket[p] = item;
  }
}

// ---------------- grouped GEMM: relu(Arow[p] @ W[e]^T) -----------------------
// 256x128x64 tiles, 512 threads = 8 waves (4m x 2n, 4x4 frags), single-buffered
// 48KB XOR-swizzled LDS (conflict-free), global_load_lds width-16 staging,
// 16x16x32 bf16 MFMA. Grid (MAXTILES, 8): expert = slot%8 -> XCD pinning.
// SCATTER=0 (layer 1): store bf16 h rows by position.
// SCATTER=1 (layer 2): atomicAdd w*relu(v) into fp32 out[token] (fused combine).
template <int GATHER, int SCATTER>
__global__ __launch_bounds__(512, 4)
void moe_gemm_k(const u16* __restrict__ A,
                const u16* __restrict__ W,
                u16* __restrict__ O,
                float* __restrict__ out,
                const float* __restrict__ wts,
                const int* __restrict__ counts,
                const int* __restrict__ offsets,
                const int* __restrict__ bucket,
                const int* __restrict__ tlist,
                const int* __restrict__ ntiles) {
  if ((int)blockIdx.x >= *ntiles) return;
  const int info = tlist[blockIdx.x];
  const int e    = info & 7;
  const int m0   = (info >> 3) << 8;   // x256 rows
  const int cnt  = counts[e];
  const int seg  = offsets[e];
  const int n0   = blockIdx.y << 7;

  __shared__ u16 As[256 * 64];  // 32 KB, [r][64] with chunk swizzle
  __shared__ u16 Bs[128 * 64];  // 16 KB

  const int tid  = threadIdx.x;
  const int lane = tid & 63;
  const int wave = tid >> 6;

  int aoff[4], boff[2];
#pragma unroll
  for (int j = 0; j < 4; ++j) {
    const int c   = ((wave << 2) + j) * 64 + lane;  // 0..2047
    const int r   = c >> 3;                         // 0..255
    const int c16 = (c & 7) ^ (r & 7);
    int p = seg + m0 + r;
    p = (p < seg + cnt) ? p : (seg + cnt - 1);      // clamp tail rows
    int rowbase;
    if (GATHER) { const int pair = bucket[p]; rowbase = (pair >> 1) * DIM; }
    else        { rowbase = p * DIM; }
    aoff[j] = rowbase + (c16 << 3);
  }
#pragma unroll
  for (int j = 0; j < 2; ++j) {
    const int c   = ((wave << 1) + j) * 64 + lane;  // 0..1023
    const int r   = c >> 3;                         // 0..127
    const int c16 = (c & 7) ^ (r & 7);
    boff[j] = e * DIM * DIM + (n0 + r) * DIM + (c16 << 3);
  }

  f32x4 acc[4][4] = {};

  const int wm   = (wave >> 1) << 6;   // 0,64,128,192
  const int wn   = (wave & 1) << 6;    // 0,64
  const int lr   = lane & 15;
  const int quad = lane >> 4;

  for (int k0 = 0; k0 < DIM; k0 += 64) {
    __syncthreads();  // protect LDS reuse
#pragma unroll
    for (int j = 0; j < 4; ++j)
      gl_lds16(A + aoff[j] + k0, &As[((wave << 2) + j) << 9]);
#pragma unroll
    for (int j = 0; j < 2; ++j)
      gl_lds16(W + boff[j] + k0, &Bs[((wave << 1) + j) << 9]);
    __syncthreads();  // drains vmcnt for global_load_lds

#pragma unroll
    for (int kk = 0; kk < 64; kk += 32) {
      const int qb = (kk >> 3) + quad;  // wanted global chunk
      short8 af[4], bf[4];
#pragma unroll
      for (int mi = 0; mi < 4; ++mi) {
        const int r = wm + (mi << 4) + lr;
        af[mi] = *(const short8*)&As[r * 64 + ((qb ^ (r & 7)) << 3)];
      }
#pragma unroll
      for (int ni = 0; ni < 4; ++ni) {
        const int r = wn + (ni << 4) + lr;
        bf[ni] = *(const short8*)&Bs[r * 64 + ((qb ^ (r & 7)) << 3)];
      }
#pragma unroll
      for (int mi = 0; mi < 4; ++mi)
#pragma unroll
        for (int ni = 0; ni < 4; ++ni)
          acc[mi][ni] = __builtin_amdgcn_mfma_f32_16x16x32_bf16(af[mi], bf[ni], acc[mi][ni], 0, 0, 0);
    }
  }

  // Epilogue. C/D layout: col = lane&15, row = quad*4 + reg.
  const int pend = seg + cnt;
#pragma unroll
  for (int mi = 0; mi < 4; ++mi) {
#pragma unroll
    for (int r4 = 0; r4 < 4; ++r4) {
      const int p = seg + m0 + wm + (mi << 4) + (quad << 2) + r4;
      if (p >= pend) continue;
      if (SCATTER) {
        const int pair = bucket[p];
        const float wv = wts[pair];
        float* orow = out + (size_t)(pair >> 1) * DIM;
#pragma unroll
        for (int ni = 0; ni < 4; ++ni) {
          const int col = n0 + wn + (ni << 4) + lr;
          float v = acc[mi][ni][r4];
          v = v > 0.f ? v : 0.f;
          atomicAdd(orow + col, wv * v);
        }
      } else {
#pragma unroll
        for (int ni = 0; ni < 4; ++ni) {
          const int col = n0 + wn + (ni << 4) + lr;
          float v = acc[mi][ni][r4];
          v = v > 0.f ? v : 0.f;
          O[(size_t)p * DIM + col] = f2bf(v);
        }
      }
    }
  }
}

extern "C" void kernel_launch(void* const* d_in, const int* in_sizes, int n_in,
                              void* d_out, int out_size, void* d_ws, size_t ws_size,
                              hipStream_t stream) {
  const float* x   = (const float*)d_in[0];
  const int*   idx = (const int*)d_in[1];
  const float* wts = (const float*)d_in[2];
  const float* W1  = (const float*)d_in[3];
  const float* W2  = (const float*)d_in[4];
  float* out = (float*)d_out;

  char* ws = (char*)d_ws;
  int* counts  = (int*)ws;                       // 8
  int* offsets = (int*)(ws + 32);                // 8
  int* ntiles  = (int*)(ws + 64);                // 1
  int* tlist   = (int*)(ws + 128);               // <=72
  int* bucket  = (int*)(ws + 1024);              // 16384
  const size_t base = 132096;                    // 16B-aligned
  const size_t MB16 = 16ull * 1024 * 1024;
  u16* xb  = (u16*)(ws + base);                  // 16 MB
  u16* w1b = (u16*)(ws + base + MB16);           // 16 MB
  u16* w2b = (u16*)(ws + base + 2 * MB16);       // 16 MB
  u16* h   = (u16*)(ws + base + 3 * MB16);       // 32 MB

  prep_k<<<1 + CASTBLK + ZEROBLK, 1024, 0, stream>>>(
      x, W1, W2, xb, w1b, w2b, idx, counts, offsets, bucket, tlist, ntiles, out);

  dim3 gg(MAXTILES, DIM / 128);  // (72, 8): x = tile slot -> XCD = expert
  moe_gemm_k<1, 0><<<gg, 512, 0, stream>>>(xb, w1b, h, nullptr, nullptr,
                                           counts, offsets, bucket, tlist, ntiles);
  moe_gemm_k<0, 1><<<gg, 512, 0, stream>>>(h, w2b, nullptr, out, wts,
                                           counts, offsets, bucket, tlist, ntiles);
}